// Round 3
// baseline (339.823 us; speedup 1.0000x reference)
//
#include <hip/hip_runtime.h>

// phase split: out[p,b,c,i,j] = x[b,c,2i+p/2,2j+p%2]
// x: [B=64, C=3, H=512, W=512] fp32 -> out: [4, B, C, 256, 256] fp32
// Pure permutation; memory-roofline bound (~402 MB traffic -> ~64 us floor).
// v3: 4 rows/thread (8 loads in flight before first use) + non-temporal
// stores (native ext_vector_type, since the builtin rejects HIP float4).

typedef float v4f __attribute__((ext_vector_type(4)));

__global__ __launch_bounds__(256) void phase_split_kernel(
    const float* __restrict__ x, float* __restrict__ out) {
    constexpr int B = 64, C = 3, H = 512, W = 512;
    constexpr int Hh = H / 2, Wh = W / 2;

    const int lane = threadIdx.x & 63;   // 8-float chunk index within a row
    const int rowi = threadIdx.x >> 6;   // 0..3: row-quad within the block
    const int h0 = blockIdx.x * 16 + rowi * 4;  // this thread: rows h0..h0+3
    const int c = blockIdx.y;                   // 0..2
    const int b = blockIdx.z;                   // 0..63

    const float* base = x + ((size_t)b * C + c) * (size_t)H * W;

    // Issue all 8 coalesced 16B loads before any use (4x MLP vs v1).
    v4f v[8];
#pragma unroll
    for (int r = 0; r < 4; ++r) {
        const v4f* src = reinterpret_cast<const v4f*>(
            base + (size_t)(h0 + r) * W) + (size_t)lane * 2;
        v[2 * r]     = src[0];
        v[2 * r + 1] = src[1];
    }

    constexpr size_t plane = (size_t)Hh * Wh;            // 65536
    constexpr size_t pstride = (size_t)B * C * plane;    // phase stride

    float* obase = out + ((size_t)b * C + c) * plane + (size_t)lane * 4;

#pragma unroll
    for (int r = 0; r < 4; ++r) {
        const int h = h0 + r;
        const int dy = h & 1;
        const int i  = h >> 1;
        const v4f a0 = v[2 * r];
        const v4f a1 = v[2 * r + 1];
        v4f ev, od;
        ev.x = a0.x; ev.y = a0.z; ev.z = a1.x; ev.w = a1.z;  // phase 2*dy
        od.x = a0.y; od.y = a0.w; od.z = a1.y; od.w = a1.w;  // phase 2*dy+1
        float* dst = obase + (size_t)(2 * dy) * pstride + (size_t)i * Wh;
        __builtin_nontemporal_store(ev, reinterpret_cast<v4f*>(dst));
        __builtin_nontemporal_store(od, reinterpret_cast<v4f*>(dst + pstride));
    }
}

extern "C" void kernel_launch(void* const* d_in, const int* in_sizes, int n_in,
                              void* d_out, int out_size, void* d_ws, size_t ws_size,
                              hipStream_t stream) {
    const float* x = (const float*)d_in[0];
    float* out = (float*)d_out;
    dim3 grid(32, 3, 64);   // 16-row groups, C, B
    dim3 block(256);
    phase_split_kernel<<<grid, block, 0, stream>>>(x, out);
}